// Round 12
// baseline (22.650 us; speedup 1.0000x reference)
//
#include <hip/hip_runtime.h>

// Problem constants (fixed by the reference)
#define NTOT 512   // N
#define NH   448   // N - K (identity head)
#define KK   64    // K (solved tail rows)
#define NL   30688 // strictly-lower entries in last K rows
#define DD   16    // domains
#define BB   1024  // batch
#define SLICES 32  // blocks per domain
#define SLCAP  32  // max samples per slice (1024/32)

// z = F_d eps, F_d = (I-L)^{-1} S  <=>  (I-L) z = S eps.
// Head: z_j = eps_j + bias_sh. Tail r: y_r = s_r*eps_{448+r} + T_r.eps[0:448];
// z_tail = (I-U)^{-1} y (63-step wave chain).
// L_emb[dom] row m: T[m][0:448] at m*448+m(m-1)/2, then U[m][0:m] at +448.
// r12: 2 same-domain samples per block (512 blocks): the 112 T-loads/wave are
// shared by both samples (wall model: blocks/CU-rounds x per-block path), both
// chains run concurrently (waves 0,1). Prefetched ballot-scan picks the pair.
// blockIdx = slice*16+dom -> all same-dom blocks on XCD dom%8 (T_d L2-local).
__global__ __launch_bounds__(256)
void fvae_fused(const float* __restrict__ eps,      // [B,512]
                const int*   __restrict__ dom_idx,  // [B]
                const float* __restrict__ L_emb,    // [16, NL]
                const float* __restrict__ S_emb,    // [16, 64]
                const float* __restrict__ bias_ns,  // [16, 64]
                const float* __restrict__ bias_sh,  // [448]
                float*       __restrict__ out)      // [B,512]
{
    const int dom   = blockIdx.x & 15;
    const int slice = blockIdx.x >> 4;
    const int tid   = threadIdx.x;
    const int wave  = tid >> 6;
    const int lane  = tid & 63;

    __shared__ int   list_s[SLCAP];
    __shared__ int   gt_s;
    __shared__ float y_s[2][KK];
    __shared__ float U_s[(KK * (KK - 1)) / 2];   // packed strictly-lower

    const float* __restrict__ Ld = L_emb + (size_t)dom * NL;

    if (wave == 0) {
        // ---- prefetched ballot-rank scan (r4-proven): one latency burst
        int dm[BB / 64];
        #pragma unroll
        for (int t = 0; t < BB / 64; ++t) dm[t] = dom_idx[t * 64 + lane];
        int base = 0;
        #pragma unroll
        for (int t = 0; t < BB / 64; ++t) {
            const unsigned long long mt = __ballot(dm[t] == dom);
            if (dm[t] == dom) {
                const int rank = base + __popcll(mt & ((1ull << lane) - 1ull));
                if ((rank & (SLICES - 1)) == slice) list_s[rank >> 5] = t * 64 + lane;
            }
            base += __popcll(mt);
        }
        if (lane == 0)
            gt_s = (base > slice) ? (base - 1 - slice) / SLICES + 1 : 0;
    } else if (dom != 0) {
        // ---- waves 1-3 stage packed U coalesced (r = 1,2,3 + 3k covers 1..63)
        for (int r = wave; r < KK; r += 3)
            if (lane < r)
                U_s[(r * (r - 1)) / 2 + lane] =
                    Ld[r * NH + (r * (r - 1)) / 2 + NH + lane];
    }
    __syncthreads();

    const int G_total = gt_s;
    if (G_total == 0) return;

    for (int s0 = 0; s0 < G_total; s0 += 2) {
        // duplicate-slot trick: odd group -> both slots same sample (writes
        // of identical values to the same address are benign)
        const int i0 = list_s[s0];
        const int i1 = list_s[(s0 + 1 < G_total) ? s0 + 1 : s0];
        const float* __restrict__ e0 = eps + (size_t)i0 * NTOT;
        const float* __restrict__ e1 = eps + (size_t)i1 * NTOT;
        float*       __restrict__ o0 = out + (size_t)i0 * NTOT;
        float*       __restrict__ o1 = out + (size_t)i1 * NTOT;

        if (dom == 0) {
            // L=0, S=I: out = eps + [bias_sh | bias_ns]; 256 quads, one/thread
            const int g = tid >> 7, q = tid & 127;
            const float* __restrict__ eb = g ? e1 : e0;
            float*       __restrict__ ob = g ? o1 : o0;
            const float4 e = *(const float4*)(eb + q * 4);
            float4 bv;
            if (q < 112) bv = *(const float4*)(bias_sh + q * 4);
            else         bv = *(const float4*)(bias_ns + (q - 112) * 4);
            float4 o; o.x = e.x + bv.x; o.y = e.y + bv.y;
            o.z = e.z + bv.z; o.w = e.w + bv.w;
            *(float4*)(ob + q * 4) = o;
            continue;   // no LDS reuse hazard (y_s untouched)
        }

        // ---- head: 224 float4 over 256 threads, one each (overlaps phase 2)
        if (tid < 2 * (NH / 4)) {
            const int g = tid / 112, q = tid - g * 112;
            const float* __restrict__ eb = g ? e1 : e0;
            float*       __restrict__ ob = g ? o1 : o0;
            const float4 e  = *(const float4*)(eb + q * 4);
            const float4 bs = *(const float4*)(bias_sh + q * 4);
            float4 o; o.x = e.x + bs.x; o.y = e.y + bs.y;
            o.z = e.z + bs.z; o.w = e.w + bs.w;
            *(float4*)(ob + q * 4) = o;
        }

        // ---- eps to registers (coalesced scalar, both samples)
        float er0[7], er1[7];
        #pragma unroll
        for (int k = 0; k < 7; ++k) er0[k] = e0[lane + 64 * k];
        #pragma unroll
        for (int k = 0; k < 7; ++k) er1[k] = e1[lane + 64 * k];

        // ---- phase 2: wave owns rows [wave*16,+16); T loads shared x2 samples
        #pragma unroll
        for (int bt = 0; bt < 4; ++bt) {
            const int r0 = wave * 16 + bt * 4;
            const float* __restrict__ T0 = Ld + (r0    ) * NH + ((r0    ) * (r0 - 1)) / 2;
            const float* __restrict__ T1 = Ld + (r0 + 1) * NH + ((r0 + 1) * (r0    )) / 2;
            const float* __restrict__ T2 = Ld + (r0 + 2) * NH + ((r0 + 2) * (r0 + 1)) / 2;
            const float* __restrict__ T3 = Ld + (r0 + 3) * NH + ((r0 + 3) * (r0 + 2)) / 2;
            float a00 = 0.f, a01 = 0.f, a02 = 0.f, a03 = 0.f;
            float a10 = 0.f, a11 = 0.f, a12 = 0.f, a13 = 0.f;
            #pragma unroll
            for (int k = 0; k < 7; ++k) {
                const float t0 = T0[lane + 64 * k], t1 = T1[lane + 64 * k],
                            t2 = T2[lane + 64 * k], t3 = T3[lane + 64 * k];
                a00 += t0 * er0[k]; a01 += t1 * er0[k];
                a02 += t2 * er0[k]; a03 += t3 * er0[k];
                a10 += t0 * er1[k]; a11 += t1 * er1[k];
                a12 += t2 * er1[k]; a13 += t3 * er1[k];
            }
            // merged butterfly reduce per sample (10 shfl each; r4-verified)
            a00 += __shfl_xor(a00, 1);  a01 += __shfl_xor(a01, 1);
            a02 += __shfl_xor(a02, 1);  a03 += __shfl_xor(a03, 1);
            float c00 = (lane & 1) ? a01 : a00;
            float c01 = (lane & 1) ? a03 : a02;
            c00 += __shfl_xor(c00, 2);  c01 += __shfl_xor(c01, 2);
            float d0 = (lane & 2) ? c01 : c00;
            d0 += __shfl_xor(d0, 4);  d0 += __shfl_xor(d0, 8);
            d0 += __shfl_xor(d0, 16); d0 += __shfl_xor(d0, 32);

            a10 += __shfl_xor(a10, 1);  a11 += __shfl_xor(a11, 1);
            a12 += __shfl_xor(a12, 1);  a13 += __shfl_xor(a13, 1);
            float c10 = (lane & 1) ? a11 : a10;
            float c11 = (lane & 1) ? a13 : a12;
            c10 += __shfl_xor(c10, 2);  c11 += __shfl_xor(c11, 2);
            float d1 = (lane & 2) ? c11 : c10;
            d1 += __shfl_xor(d1, 4);  d1 += __shfl_xor(d1, 8);
            d1 += __shfl_xor(d1, 16); d1 += __shfl_xor(d1, 32);

            if (lane < 4) {
                const int r = r0 + lane;
                const float sr = S_emb[dom * KK + r];
                y_s[0][r] = d0 + sr * e0[NH + r];
                y_s[1][r] = d1 + sr * e1[NH + r];
            }
        }
        __syncthreads();

        // ---- phase 3: wave 0 solves sample 0, wave 1 sample 1, concurrently
        if (wave < 2) {
            const float* __restrict__ eb = wave ? e1 : e0; (void)eb;
            float*       __restrict__ ob = wave ? o1 : o0;
            const int m  = lane;
            const int tb = (m * (m - 1)) / 2;
            float z = y_s[wave][m];
            #pragma unroll
            for (int r = 0; r < KK - 1; ++r) {
                const float u = (r < m) ? U_s[tb + r] : 0.f;
                z += u * __shfl(z, r);           // lane r's z final by step r
            }
            ob[NH + m] = z + bias_ns[dom * KK + m];
        }
        if (s0 + 2 < G_total) __syncthreads();   // protect y_s for next group
    }
}

extern "C" void kernel_launch(void* const* d_in, const int* in_sizes, int n_in,
                              void* d_out, int out_size, void* d_ws, size_t ws_size,
                              hipStream_t stream) {
    const float* eps     = (const float*)d_in[0];
    const int*   dom     = (const int*)  d_in[1];
    const float* L_emb   = (const float*)d_in[2];
    const float* S_emb   = (const float*)d_in[3];
    const float* bias_ns = (const float*)d_in[4];
    const float* bias_sh = (const float*)d_in[5];
    float* out = (float*)d_out;

    fvae_fused<<<dim3(DD * SLICES), dim3(256), 0, stream>>>(
        eps, dom, L_emb, S_emb, bias_ns, bias_sh, out);
}

// Round 13
// 15.466 us; speedup vs baseline: 1.4645x; 1.4645x over previous
//
#include <hip/hip_runtime.h>

// Problem constants (fixed by the reference)
#define NTOT 512   // N
#define NH   448   // N - K (identity head)
#define KK   64    // K (solved tail rows)
#define NL   30688 // strictly-lower entries in last K rows
#define DD   16    // domains

// z = F_d eps, F_d = (I-L)^{-1} S  <=>  (I-L) z = S eps.
// Head: z_j = eps_j + bias_sh. Tail r: y_r = s_r*eps_{448+r} + T_r.eps[0:448];
// z_tail = (I-U)^{-1} y (63-step wave chain).
// L_emb[dom] row m: T[m][0:448] at m*448+m(m-1)/2, then U[m][0:m] at +448.
// r13: r10's shape (1024 blocks, 1 sample each) but 512-thread blocks with
// __launch_bounds__(512,8): 4 blocks/CU x 8 waves = 32 waves/CU (vs r10's 16)
// -> 2x the wave-level latency hiding. Requires VGPR<=64, so eps lives in LDS
// and phase-2 uses 2-row batches (14 in-flight loads, ~40 live VGPRs).
__global__ __launch_bounds__(512, 8)
void fvae_fused(const float* __restrict__ eps,      // [B,512]
                const int*   __restrict__ dom_idx,  // [B]
                const float* __restrict__ L_emb,    // [16, NL]
                const float* __restrict__ S_emb,    // [16, 64]
                const float* __restrict__ bias_ns,  // [16, 64]
                const float* __restrict__ bias_sh,  // [448]
                float*       __restrict__ out)      // [B,512]
{
    const int b    = blockIdx.x;
    const int tid  = threadIdx.x;
    const int wave = tid >> 6;      // 0..7
    const int lane = tid & 63;

    __shared__ float eps_s[NTOT];
    __shared__ float y_s[KK];
    __shared__ float U_s[(KK * (KK - 1)) / 2];   // packed strictly-lower (7.9 KB)

    const int dom = dom_idx[b];
    const float* __restrict__ epsb = eps + (size_t)b * NTOT;
    float*       __restrict__ outb = out + (size_t)b * NTOT;

    if (dom == 0) {
        // L=0, S=I: out = eps + [bias_sh | bias_ns]; 128 quads
        if (tid < 128) {
            const float4 e = *(const float4*)(epsb + tid * 4);
            float4 bv;
            if (tid < 112) bv = *(const float4*)(bias_sh + tid * 4);
            else           bv = *(const float4*)(bias_ns + (tid - 112) * 4);
            float4 o; o.x = e.x + bv.x; o.y = e.y + bv.y;
            o.z = e.z + bv.z; o.w = e.w + bv.w;
            *(float4*)(outb + tid * 4) = o;
        }
        return;
    }

    const float* __restrict__ Ld = L_emb + (size_t)dom * NL;

    // ---- stage eps: one float per thread (coalesced)
    eps_s[tid] = epsb[tid];

    // ---- waves 1..7 stage packed U coalesced (r = wave + 7k covers 1..63)
    if (wave != 0) {
        for (int r = wave; r < KK; r += 7)
            if (lane < r)
                U_s[(r * (r - 1)) / 2 + lane] =
                    Ld[r * NH + (r * (r - 1)) / 2 + NH + lane];
    }
    __syncthreads();

    // ---- head: out[:,0:448] = eps + bias_sh (112 quads; eps from LDS)
    if (tid < NH / 4) {
        const float4 e  = *(const float4*)&eps_s[tid * 4];
        const float4 bs = *(const float4*)(bias_sh + tid * 4);
        float4 o; o.x = e.x + bs.x; o.y = e.y + bs.y;
        o.z = e.z + bs.z; o.w = e.w + bs.w;
        *(float4*)(outb + tid * 4) = o;
    }

    // ---- eps slice to registers (LDS, stride 64 = 2-way free)
    float er[7];
    #pragma unroll
    for (int k = 0; k < 7; ++k) er[k] = eps_s[lane + 64 * k];

    // ---- phase 2: wave owns rows [wave*8, +8), 4 batches of 2 rows
    #pragma unroll
    for (int bt = 0; bt < 4; ++bt) {
        const int r0 = wave * 8 + bt * 2;
        const float* __restrict__ T0 = Ld + (r0    ) * NH + ((r0    ) * (r0 - 1)) / 2;
        const float* __restrict__ T1 = Ld + (r0 + 1) * NH + ((r0 + 1) * (r0    )) / 2;
        float a0 = T0[lane]*er[0] + T0[lane+64]*er[1] + T0[lane+128]*er[2]
                 + T0[lane+192]*er[3] + T0[lane+256]*er[4] + T0[lane+320]*er[5]
                 + T0[lane+384]*er[6];
        float a1 = T1[lane]*er[0] + T1[lane+64]*er[1] + T1[lane+128]*er[2]
                 + T1[lane+192]*er[3] + T1[lane+256]*er[4] + T1[lane+320]*er[5]
                 + T1[lane+384]*er[6];
        // merged 2-row butterfly reduce: 6 shfls; lane 0 -> row r0, lane 1 -> r0+1
        a0 += __shfl_xor(a0, 1);
        a1 += __shfl_xor(a1, 1);
        float c = (lane & 1) ? a1 : a0;
        c += __shfl_xor(c, 2);
        c += __shfl_xor(c, 4);
        c += __shfl_xor(c, 8);
        c += __shfl_xor(c, 16);
        c += __shfl_xor(c, 32);
        if (lane < 2) {
            const int r = r0 + lane;
            y_s[r] = c + S_emb[dom * KK + r] * eps_s[NH + r];
        }
    }
    __syncthreads();

    // ---- phase 3: wave 0; U_s read directly (addresses chain-independent)
    if (wave == 0) {
        const int m  = lane;
        const int tb = (m * (m - 1)) / 2;
        float z = y_s[m];
        #pragma unroll
        for (int r = 0; r < KK - 1; ++r) {
            const float u = (r < m) ? U_s[tb + r] : 0.f;
            z += u * __shfl(z, r);               // lane r's z final by step r
        }
        outb[NH + m] = z + bias_ns[dom * KK + m];
    }
}

extern "C" void kernel_launch(void* const* d_in, const int* in_sizes, int n_in,
                              void* d_out, int out_size, void* d_ws, size_t ws_size,
                              hipStream_t stream) {
    const float* eps     = (const float*)d_in[0];
    const int*   dom     = (const int*)  d_in[1];
    const float* L_emb   = (const float*)d_in[2];
    const float* S_emb   = (const float*)d_in[3];
    const float* bias_ns = (const float*)d_in[4];
    const float* bias_sh = (const float*)d_in[5];
    float* out = (float*)d_out;

    const int B = in_sizes[0] / NTOT;   // 1024
    fvae_fused<<<dim3(B), dim3(512), 0, stream>>>(eps, dom, L_emb, S_emb,
                                                  bias_ns, bias_sh, out);
}